// Round 6
// baseline (436.767 us; speedup 1.0000x reference)
//
#include <hip/hip_runtime.h>
#include <hip/hip_bf16.h>

// TriangleAttentionStartingNode  B=1, N=256, C_Z=128, H=4, D=32, TOTAL=128
// Round 11: TLP attack on the latency-bound regime.
//   Round-10 post-mortem: FETCH 123->28 MB as predicted but dur unchanged
//   (63.9 us) -> never BW-bound. MfmaUtil 12.6 / VALU 27 / Occ 35 / HBM 11:
//   latency-bound, ~160 dependent L2 loads per wave at ~200cy with VGPR=64
//   (no prefetch depth) and only 4 waves/SIMD to hide them.
//   Fix: same per-block work split across 8 waves (512 thr), each wave owns
//   32 rows -> serial chain halves; 4 blk/CU x 8 waves = 32 waves/CU = 100%
//   occupancy at the 64-VGPR footprint (launch_bounds(512,8) pins cap 64).
//   Plus: BbF accumulator load prefetched one kh ahead (8 VGPR).
//   XCD co-location swizzle kept (keeps loads L2-hit, 200cy not 900).

#define QSCALE 0.17677669529663687f  // 1/sqrt(32)

typedef __attribute__((ext_vector_type(8))) short bf16x8;
typedef __attribute__((ext_vector_type(4))) short bf16x4;
typedef __attribute__((ext_vector_type(4))) float f32x4;

#define MFMA32(a, b, c) __builtin_amdgcn_mfma_f32_16x16x32_bf16((a), (b), (c), 0, 0, 0)

__device__ __forceinline__ f32x4 mfma16_asm(bf16x4 a, bf16x4 b, f32x4 c) {
    f32x4 d;
    asm volatile("v_mfma_f32_16x16x16_bf16 %0, %1, %2, %3"
                 : "=v"(d) : "v"(a), "v"(b), "v"(c));
    return d;
}

#if !defined(__HIP_DEVICE_COMPILE__)
#define MFMA16(a, b, c) (c)   /* host pass: parsed only, never executed */
#elif __has_builtin(__builtin_amdgcn_mfma_f32_16x16x16bf16_1k)
#define MFMA16(a, b, c) __builtin_amdgcn_mfma_f32_16x16x16bf16_1k((a), (b), (c), 0, 0, 0)
#else
#define MFMA16(a, b, c) mfma16_asm((a), (b), (c))
#endif

__device__ __forceinline__ ushort f2bf(float f) {
    uint32_t u = __builtin_bit_cast(uint32_t, f);
    uint32_t r = (u + 0x7FFFu + ((u >> 16) & 1u)) >> 16;  // RNE
    return (ushort)r;
}
__device__ __forceinline__ uint pk2(float a, float b) {   // v_cvt_pk_bf16_f32
    union { __hip_bfloat162 h; uint u; } cv;
    cv.h = __float22bfloat162_rn(make_float2(a, b));
    return cv.u;
}

// ---------------------------------------------------------------------------
// prep_bias: bid<320 -> prep: Wfrag[ct][ks][lane][j] bf16 with
//   n = ct*16+(lane&15), k = ks*32+(lane>>4)*8+j, value W^T[n][k]
//   (n: 0..127 Wq*QSCALE, 128..255 Wk, 256..383 Wv, 384..511 Wg); WoFrag same.
// bid>=320 -> bias: LN in-register; write xn bf16 [p][128]; dot with Wb ->
//   BbF fp32 scattered in attn-frag order (row=j, col=k):
//   addr = (((h*16+j/16)*16+k/16)*64 + ((k&15)>>2)*16 + (j&15))*4 + (k&3)
// ---------------------------------------------------------------------------
__global__ __launch_bounds__(256) void prep_bias_kernel(
    const float* __restrict__ Wq, const float* __restrict__ Wk, const float* __restrict__ Wv,
    const float* __restrict__ Wg, const float* __restrict__ Wo, const float* __restrict__ Wb,
    const float* __restrict__ x, const float* __restrict__ gamma, const float* __restrict__ beta,
    ushort* __restrict__ Wfrag, ushort* __restrict__ WoFrag,
    ushort* __restrict__ xn, float* __restrict__ BbF)
{
    __shared__ float WbS[512];
    __shared__ float gS[128];
    __shared__ float bS[128];

    if (blockIdx.x < 320) {
        int idx = blockIdx.x * 256 + threadIdx.x;
        if (idx < 65536) {
            int j = idx & 7, lane = (idx >> 3) & 63, ks = (idx >> 9) & 3, ct = idx >> 11;
            int n = ct * 16 + (lane & 15);
            int k = ks * 32 + (lane >> 4) * 8 + j;
            float v;
            if (n < 128)      v = Wq[k * 128 + n] * QSCALE;
            else if (n < 256) v = Wk[k * 128 + (n - 128)];
            else if (n < 384) v = Wv[k * 128 + (n - 256)];
            else              v = Wg[k * 128 + (n - 384)];
            Wfrag[idx] = f2bf(v);
        } else {
            int idx2 = idx - 65536;
            int j = idx2 & 7, lane = (idx2 >> 3) & 63, ks = (idx2 >> 9) & 3, ct = idx2 >> 11;
            int n = ct * 16 + (lane & 15);
            int k = ks * 32 + (lane >> 4) * 8 + j;
            WoFrag[idx2] = f2bf(Wo[k * 128 + n]);
        }
        return;
    }

    const int t = threadIdx.x;
    if (t < 128)      { *(f32x4*)&WbS[t * 4] = *(const f32x4*)(Wb + t * 4); }
    else if (t < 160) { int c = (t - 128) * 4; *(f32x4*)&gS[c] = *(const f32x4*)(gamma + c); }
    else if (t < 192) { int c = (t - 160) * 4; *(f32x4*)&bS[c] = *(const f32x4*)(beta + c); }
    __syncthreads();

    const int wave = t >> 6, lane = t & 63, m = lane & 15, quad = lane >> 4;
    const int p = (blockIdx.x - 320) * 64 + wave * 16 + m;

    const float* rp0 = x + (size_t)p * 128;
    f32x4 xa[4][2];
    float sum = 0.f, ssq = 0.f;
#pragma unroll
    for (int ks = 0; ks < 4; ++ks) {
        xa[ks][0] = *(const f32x4*)(rp0 + ks * 32 + quad * 8);
        xa[ks][1] = *(const f32x4*)(rp0 + ks * 32 + quad * 8 + 4);
#pragma unroll
        for (int q4 = 0; q4 < 2; ++q4) {
            f32x4 v = xa[ks][q4];
            sum += v[0] + v[1] + v[2] + v[3];
            ssq += v[0]*v[0] + v[1]*v[1] + v[2]*v[2] + v[3]*v[3];
        }
    }
    sum += __shfl_xor(sum, 16); ssq += __shfl_xor(ssq, 16);
    sum += __shfl_xor(sum, 32); ssq += __shfl_xor(ssq, 32);
    const float mu   = sum * (1.f / 128.f);
    const float rstd = rsqrtf(ssq * (1.f / 128.f) - mu * mu + 1e-5f);

    float b0 = 0.f, b1 = 0.f, b2 = 0.f, b3 = 0.f;
#pragma unroll
    for (int ks = 0; ks < 4; ++ks) {
        uint4 pkd;
        uint pw[4];
#pragma unroll
        for (int q4 = 0; q4 < 2; ++q4) {
            const int c = ks * 32 + quad * 8 + q4 * 4;
            f32x4 v = xa[ks][q4];
            float n0 = (v[0] - mu) * rstd * gS[c + 0] + bS[c + 0];
            float n1 = (v[1] - mu) * rstd * gS[c + 1] + bS[c + 1];
            float n2 = (v[2] - mu) * rstd * gS[c + 2] + bS[c + 2];
            float n3 = (v[3] - mu) * rstd * gS[c + 3] + bS[c + 3];
            pw[q4 * 2]     = pk2(n0, n1);
            pw[q4 * 2 + 1] = pk2(n2, n3);
            f32x4 w0 = *(const f32x4*)&WbS[(c + 0) * 4];
            f32x4 w1 = *(const f32x4*)&WbS[(c + 1) * 4];
            f32x4 w2 = *(const f32x4*)&WbS[(c + 2) * 4];
            f32x4 w3 = *(const f32x4*)&WbS[(c + 3) * 4];
            b0 += n0*w0[0] + n1*w1[0] + n2*w2[0] + n3*w3[0];
            b1 += n0*w0[1] + n1*w1[1] + n2*w2[1] + n3*w3[1];
            b2 += n0*w0[2] + n1*w1[2] + n2*w2[2] + n3*w3[2];
            b3 += n0*w0[3] + n1*w1[3] + n2*w2[3] + n3*w3[3];
        }
        pkd.x = pw[0]; pkd.y = pw[1]; pkd.z = pw[2]; pkd.w = pw[3];
        *(uint4*)(xn + (size_t)p * 128 + ks * 32 + quad * 8) = pkd;
    }
    b0 += __shfl_xor(b0, 16); b1 += __shfl_xor(b1, 16); b2 += __shfl_xor(b2, 16); b3 += __shfl_xor(b3, 16);
    b0 += __shfl_xor(b0, 32); b1 += __shfl_xor(b1, 32); b2 += __shfl_xor(b2, 32); b3 += __shfl_xor(b3, 32);

    if (quad == 0) {
        const int row = p >> 8, col = p & 255;
        float bb[4] = {b0, b1, b2, b3};
#pragma unroll
        for (int r = 0; r < 4; ++r) {
            int addr = (((r * 16 + (row >> 4)) * 16 + (col >> 4)) * 64 +
                        ((col & 15) >> 2) * 16 + (row & 15)) * 4 + (col & 3);
            BbF[addr] = bb[r];
        }
    }
}

// ---------------------------------------------------------------------------
// fused: grid 1024, 512 thr = 8 waves, 37376 B LDS -> 4 blocks/CU = 32 waves.
// XCD co-location: i = ((bid>>5)<<3)|(bid&7), h = (bid>>3)&3.
// Wave w owns 32 j-rows [w*32, w*32+32) for proj AND attention.
// LDS: QK region [256][40] ushort (Qtmp, then K [k][d], pad-40);
//      VT region [32][264] ushort (V^T [d][k], pad-264).
// Phases: Qproj -> qf (same-wave rows, no barrier) -> Kproj -> Vproj ->
//         barrier -> attention (P in-register, BbF prefetched 1 kh ahead) ->
//         Gproj+gate+store (fused; G acc layout == O acc layout).
// ---------------------------------------------------------------------------
__global__ __launch_bounds__(512, 8) void fused_kernel(
    const ushort* __restrict__ xn, const ushort* __restrict__ Wfrag,
    const float* __restrict__ bg, const float* __restrict__ BbF,
    ushort* __restrict__ gvals)
{
    __shared__ __align__(16) ushort SM[18688];
    ushort* QK = SM;            // [256][40]: Qtmp, then K [k][d]
    ushort* VT = SM + 10240;    // [32][264]: V^T [d][k]

    const int t = threadIdx.x;
    const int w = t >> 6, lane = t & 63, m = lane & 15, quad = lane >> 4;
    const int b = blockIdx.x;
    const int i = ((b >> 5) << 3) | (b & 7);   // same-i blocks: same XCD (mod 8)
    const int h = (b >> 3) & 3;                //   and same 32-block window
    const ushort* xb = xn + ((size_t)i << 15);   // i*256*128

    // ---- Q proj -> Qtmp [j][40] (wave's 32 rows) ----
    {
        const ushort* Wm = Wfrag + (0 + h * 2) * 2048;
        bf16x8 wfr[2][4];
#pragma unroll
        for (int ctl = 0; ctl < 2; ++ctl)
#pragma unroll
            for (int ks = 0; ks < 4; ++ks)
                wfr[ctl][ks] = *(const bf16x8*)(Wm + ctl * 2048 + ks * 512 + lane * 8);
#pragma unroll
        for (int grp = 0; grp < 2; ++grp) {
            const int j = w * 32 + grp * 16 + m;
            bf16x8 xg[4];
            const ushort* xp = xb + (size_t)j * 128 + quad * 8;
#pragma unroll
            for (int ks = 0; ks < 4; ++ks) xg[ks] = *(const bf16x8*)(xp + ks * 32);
#pragma unroll
            for (int ctl = 0; ctl < 2; ++ctl) {
                f32x4 acc = (f32x4){0.f, 0.f, 0.f, 0.f};
#pragma unroll
                for (int ks = 0; ks < 4; ++ks) acc = MFMA32(wfr[ctl][ks], xg[ks], acc);
                uint2 u; u.x = pk2(acc[0], acc[1]); u.y = pk2(acc[2], acc[3]);
                *(uint2*)(QK + j * 40 + ctl * 16 + quad * 4) = u;
            }
        }
    }
    // qf: same-wave rows -> no barrier needed (lgkmcnt ordering suffices)
    bf16x8 qf[2];                           // B-frags: lane = j, elems = d
#pragma unroll
    for (int jt = 0; jt < 2; ++jt)
        qf[jt] = *(const bf16x8*)(QK + (w * 32 + jt * 16 + m) * 40 + quad * 8);
    asm volatile("" ::: "memory");          // block load-CSE across phases

    // ---- K proj -> QK region as K [k][40] (same-wave rows overwrite) ----
    {
        const ushort* Wm = Wfrag + (8 + h * 2) * 2048;
        bf16x8 wfr[2][4];
#pragma unroll
        for (int ctl = 0; ctl < 2; ++ctl)
#pragma unroll
            for (int ks = 0; ks < 4; ++ks)
                wfr[ctl][ks] = *(const bf16x8*)(Wm + ctl * 2048 + ks * 512 + lane * 8);
#pragma unroll
        for (int grp = 0; grp < 2; ++grp) {
            const int k = w * 32 + grp * 16 + m;
            bf16x8 xg[4];
            const ushort* xp = xb + (size_t)k * 128 + quad * 8;
#pragma unroll
            for (int ks = 0; ks < 4; ++ks) xg[ks] = *(const bf16x8*)(xp + ks * 32);
#pragma unroll
            for (int ctl = 0; ctl < 2; ++ctl) {
                f32x4 acc = (f32x4){0.f, 0.f, 0.f, 0.f};
#pragma unroll
                for (int ks = 0; ks < 4; ++ks) acc = MFMA32(wfr[ctl][ks], xg[ks], acc);
                uint2 u; u.x = pk2(acc[0], acc[1]); u.y = pk2(acc[2], acc[3]);
                *(uint2*)(QK + k * 40 + ctl * 16 + quad * 4) = u;
            }
        }
    }
    asm volatile("" ::: "memory");

    // ---- V proj -> VT [d][264] (transposed) ----
    {
        const ushort* Wm = Wfrag + (16 + h * 2) * 2048;
        bf16x8 wfr[2][4];
#pragma unroll
        for (int ctl = 0; ctl < 2; ++ctl)
#pragma unroll
            for (int ks = 0; ks < 4; ++ks)
                wfr[ctl][ks] = *(const bf16x8*)(Wm + ctl * 2048 + ks * 512 + lane * 8);
#pragma unroll
        for (int grp = 0; grp < 2; ++grp) {
            const int k = w * 32 + grp * 16 + m;
            bf16x8 xg[4];
            const ushort* xp = xb + (size_t)k * 128 + quad * 8;
#pragma unroll
            for (int ks = 0; ks < 4; ++ks) xg[ks] = *(const bf16x8*)(xp + ks * 32);
#pragma unroll
            for (int ctl = 0; ctl < 2; ++ctl) {
                f32x4 acc = (f32x4){0.f, 0.f, 0.f, 0.f};
#pragma unroll
                for (int ks = 0; ks < 4; ++ks) acc = MFMA32(wfr[ctl][ks], xg[ks], acc);
#pragma unroll
                for (int r = 0; r < 4; ++r)
                    VT[(ctl * 16 + quad * 4 + r) * 264 + k] = f2bf(acc[r]);
            }
        }
    }
    __syncthreads();    // K, VT visible to all waves

    // ---- attention: 16-wide k-tiles; P in registers; BbF prefetch 1 ahead --
    f32x4 O[2][2];
    float lsum[2];
#pragma unroll
    for (int jt = 0; jt < 2; ++jt) {
        O[jt][0] = (f32x4){0.f, 0.f, 0.f, 0.f};
        O[jt][1] = (f32x4){0.f, 0.f, 0.f, 0.f};
        lsum[jt] = 0.f;
    }
    const float* bb = BbF + ((size_t)(h * 16 + w * 2) << 12) + (lane << 2);

    f32x4 Scur[2], Snxt[2];
    Scur[0] = *(const f32x4*)(bb);
    Scur[1] = *(const f32x4*)(bb + 4096);

    for (int kh = 0; kh < 16; ++kh) {
        if (kh < 15) {
            Snxt[0] = *(const f32x4*)(bb + ((kh + 1) << 8));
            Snxt[1] = *(const f32x4*)(bb + 4096 + ((kh + 1) << 8));
        }
        bf16x8 kf = *(const bf16x8*)(QK + (kh * 16 + m) * 40 + quad * 8);  // A: lane=k, elems=d
        bf16x4 vf[2];                                                       // A: lane=d, elems=k
#pragma unroll
        for (int dt = 0; dt < 2; ++dt) {
            uint2 vv = *(const uint2*)(VT + (dt * 16 + m) * 264 + kh * 16 + quad * 4);
            vf[dt] = __builtin_bit_cast(bf16x4, vv);
        }
#pragma unroll
        for (int jt = 0; jt < 2; ++jt) {
            f32x4 S = MFMA32(kf, qf[jt], Scur[jt]);
            float p0 = __expf(S[0]), p1 = __expf(S[1]);
            float p2 = __expf(S[2]), p3 = __expf(S[3]);
            lsum[jt] += p0 + p1 + p2 + p3;
            uint2 pu; pu.x = pk2(p0, p1); pu.y = pk2(p2, p3);
            bf16x4 pf = __builtin_bit_cast(bf16x4, pu);   // B: lane=j, k=quad*4+e
#pragma unroll
            for (int dt = 0; dt < 2; ++dt)
                O[jt][dt] = MFMA16(vf[dt], pf, O[jt][dt]);
        }
        Scur[0] = Snxt[0];
        Scur[1] = Snxt[1];
    }

    // row sums across quads
#pragma unroll
    for (int jt = 0; jt < 2; ++jt) {
        float s = lsum[jt];
        s += __shfl_xor(s, 16);
        s += __shfl_xor(s, 32);
        lsum[jt] = 1.f / s;
    }

    // ---- G proj fused with gating + store (G acc layout == O acc layout) ----
    {
        const ushort* Wm = Wfrag + (24 + h * 2) * 2048;
        bf16x8 wfr[2][4];
        f32x4 bg4[2];
#pragma unroll
        for (int ctl = 0; ctl < 2; ++ctl) {
#pragma unroll
            for (int ks = 0; ks < 4; ++ks)
                wfr[ctl][ks] = *(const bf16x8*)(Wm + ctl * 2048 + ks * 512 + lane * 8);
            bg4[ctl] = *(const f32x4*)(bg + h * 32 + ctl * 16 + quad * 4);
        }
#pragma unroll
        for (int grp = 0; grp < 2; ++grp) {
            const int j = w * 32 + grp * 16 + m;
            const float rl = lsum[grp];
            bf16x8 xg[4];
            const ushort* xp = xb + (size_t)j * 128 + quad * 8;
#pragma unroll
            for (int ks = 0; ks < 4; ++ks) xg[ks] = *(const bf16x8*)(xp + ks * 32);
#pragma unroll
            for (int ctl = 0; ctl < 2; ++ctl) {
                f32x4 acc = (f32x4){0.f, 0.f, 0.f, 0.f};
#pragma unroll
                for (int ks = 0; ks < 4; ++ks) acc = MFMA32(wfr[ctl][ks], xg[ks], acc);
                float g0 = 1.f / (1.f + __expf(-(acc[0] + bg4[ctl][0])));
                float g1 = 1.f / (1.f + __expf(-(acc[1] + bg4[ctl][1])));
                float g2 = 1.f / (1.f + __expf(-(acc[2] + bg4[ctl][2])));
                float g3 = 1.f / (1.f + __expf(-(acc[3] + bg4[ctl][3])));
                float v0 = O[grp][ctl][0] * rl * g0;
                float v1 = O[grp][ctl][1] * rl * g1;
                float v2 = O[grp][ctl][2] * rl * g2;
                float v3 = O[grp][ctl][3] * rl * g3;
                uint2 u; u.x = pk2(v0, v1); u.y = pk2(v2, v3);
                *(uint2*)(gvals + (size_t)(i * 256 + j) * 128 + h * 32 + ctl * 16 + quad * 4) = u;
            }
        }
    }
}

// ---------------------------------------------------------------------------
// oproj: A = WoFrag, B = gvals rows -> D[ncol][p]; float4 stores + bo.
// ---------------------------------------------------------------------------
__global__ __launch_bounds__(256) void oproj_kernel(
    const ushort* __restrict__ gvals, const ushort* __restrict__ WoFrag,
    const float* __restrict__ bo, float* __restrict__ out)
{
    __shared__ ushort Bs[8 * 2048];
    const int t = threadIdx.x;
    const int wave = t >> 6, lane = t & 63, m = lane & 15, quad = lane >> 4;
    const int p0 = blockIdx.x * 64;
    {
        const uint4* src = (const uint4*)WoFrag;
        uint4* dst = (uint4*)Bs;
#pragma unroll
        for (int r = 0; r < 8; ++r) dst[r * 256 + t] = src[r * 256 + t];
    }
    bf16x8 gf[4];
    const int p = p0 + wave * 16 + m;
#pragma unroll
    for (int ks = 0; ks < 4; ++ks)
        gf[ks] = *(const bf16x8*)(gvals + (size_t)p * 128 + ks * 32 + quad * 8);
    __syncthreads();

#pragma unroll
    for (int ct = 0; ct < 8; ++ct) {
        f32x4 acc = (f32x4){0.f, 0.f, 0.f, 0.f};
#pragma unroll
        for (int ks = 0; ks < 4; ++ks) {
            bf16x8 wfr = ((const bf16x8*)Bs)[(ct * 4 + ks) * 64 + lane];
            acc = MFMA32(wfr, gf[ks], acc);
        }
        const int c0 = ct * 16 + quad * 4;
        f32x4 bov = *(const f32x4*)(bo + c0);
        float4 v = make_float4(acc[0] + bov[0], acc[1] + bov[1],
                               acc[2] + bov[2], acc[3] + bov[3]);
        *(float4*)(&out[(size_t)p * 128 + c0]) = v;
    }
}

// ---------------------------------------------------------------------------
extern "C" void kernel_launch(void* const* d_in, const int* in_sizes, int n_in,
                              void* d_out, int out_size, void* d_ws, size_t ws_size,
                              hipStream_t stream) {
    const float* x     = (const float*)d_in[0];
    const float* gamma = (const float*)d_in[1];
    const float* beta  = (const float*)d_in[2];
    const float* Wq    = (const float*)d_in[3];
    const float* Wk    = (const float*)d_in[4];
    const float* Wv    = (const float*)d_in[5];
    const float* Wb    = (const float*)d_in[6];
    const float* Wg    = (const float*)d_in[7];
    const float* bg    = (const float*)d_in[8];
    const float* Wo    = (const float*)d_in[9];
    const float* bo    = (const float*)d_in[10];

    ushort* ws      = (ushort*)d_ws;
    ushort* Wfrag   = ws;                                // 65536 ushorts
    ushort* WoFragp = ws + 65536;                        // 16384 ushorts
    ushort* xn      = ws + 81920;                        // 8388608 ushorts (16 MB)
    ushort* gvals   = ws + 81920 + 8388608;              // 8388608 ushorts (16 MB)
    float*  BbF     = (float*)(ws + 81920 + 2 * 8388608);  // 262144 fp32 (1 MB)

    prep_bias_kernel<<<1344, 256, 0, stream>>>(Wq, Wk, Wv, Wg, Wo, Wb,
                                               x, gamma, beta,
                                               Wfrag, WoFragp, xn, BbF);
    fused_kernel<<<1024, 512, 0, stream>>>(xn, Wfrag, bg, BbF, gvals);
    oproj_kernel<<<1024, 256, 0, stream>>>(gvals, WoFragp, bo, (float*)d_out);
}

// Round 7
// 192.707 us; speedup vs baseline: 2.2665x; 2.2665x over previous
//
#include <hip/hip_runtime.h>
#include <hip/hip_bf16.h>

// TriangleAttentionStartingNode  B=1, N=256, C_Z=128, H=4, D=32, TOTAL=128
// Round 12: round-11 with the spill fixed (single surgical change).
//   Round-11 post-mortem: launch_bounds(512,8) -> <=64 VGPR cap, allocator
//   landed at 32 vs a ~100-VGPR live set -> everything spilled to scratch
//   (FETCH 370 MB, WRITE 608 MB, 1 GB traffic = the whole 323 us, MfmaUtil
//   2.6%). The TLP hypothesis was never actually tested.
//   Fix: launch_bounds(512,4) -> 128-VGPR cap, no spills. 8-wave blocks,
//   halved per-wave chain, BbF prefetch, XCD co-location all kept.
//   If VGPR <=64: 4 blk/CU x 8 waves = 32 waves/CU; if 65..128: 16 waves/CU
//   (= round-10 TLP with half the dependent-load chain per wave).

#define QSCALE 0.17677669529663687f  // 1/sqrt(32)

typedef __attribute__((ext_vector_type(8))) short bf16x8;
typedef __attribute__((ext_vector_type(4))) short bf16x4;
typedef __attribute__((ext_vector_type(4))) float f32x4;

#define MFMA32(a, b, c) __builtin_amdgcn_mfma_f32_16x16x32_bf16((a), (b), (c), 0, 0, 0)

__device__ __forceinline__ f32x4 mfma16_asm(bf16x4 a, bf16x4 b, f32x4 c) {
    f32x4 d;
    asm volatile("v_mfma_f32_16x16x16_bf16 %0, %1, %2, %3"
                 : "=v"(d) : "v"(a), "v"(b), "v"(c));
    return d;
}

#if !defined(__HIP_DEVICE_COMPILE__)
#define MFMA16(a, b, c) (c)   /* host pass: parsed only, never executed */
#elif __has_builtin(__builtin_amdgcn_mfma_f32_16x16x16bf16_1k)
#define MFMA16(a, b, c) __builtin_amdgcn_mfma_f32_16x16x16bf16_1k((a), (b), (c), 0, 0, 0)
#else
#define MFMA16(a, b, c) mfma16_asm((a), (b), (c))
#endif

__device__ __forceinline__ ushort f2bf(float f) {
    uint32_t u = __builtin_bit_cast(uint32_t, f);
    uint32_t r = (u + 0x7FFFu + ((u >> 16) & 1u)) >> 16;  // RNE
    return (ushort)r;
}
__device__ __forceinline__ uint pk2(float a, float b) {   // v_cvt_pk_bf16_f32
    union { __hip_bfloat162 h; uint u; } cv;
    cv.h = __float22bfloat162_rn(make_float2(a, b));
    return cv.u;
}

// ---------------------------------------------------------------------------
// prep_bias: bid<320 -> prep: Wfrag[ct][ks][lane][j] bf16 with
//   n = ct*16+(lane&15), k = ks*32+(lane>>4)*8+j, value W^T[n][k]
//   (n: 0..127 Wq*QSCALE, 128..255 Wk, 256..383 Wv, 384..511 Wg); WoFrag same.
// bid>=320 -> bias: LN in-register; write xn bf16 [p][128]; dot with Wb ->
//   BbF fp32 scattered in attn-frag order (row=j, col=k):
//   addr = (((h*16+j/16)*16+k/16)*64 + ((k&15)>>2)*16 + (j&15))*4 + (k&3)
// ---------------------------------------------------------------------------
__global__ __launch_bounds__(256) void prep_bias_kernel(
    const float* __restrict__ Wq, const float* __restrict__ Wk, const float* __restrict__ Wv,
    const float* __restrict__ Wg, const float* __restrict__ Wo, const float* __restrict__ Wb,
    const float* __restrict__ x, const float* __restrict__ gamma, const float* __restrict__ beta,
    ushort* __restrict__ Wfrag, ushort* __restrict__ WoFrag,
    ushort* __restrict__ xn, float* __restrict__ BbF)
{
    __shared__ float WbS[512];
    __shared__ float gS[128];
    __shared__ float bS[128];

    if (blockIdx.x < 320) {
        int idx = blockIdx.x * 256 + threadIdx.x;
        if (idx < 65536) {
            int j = idx & 7, lane = (idx >> 3) & 63, ks = (idx >> 9) & 3, ct = idx >> 11;
            int n = ct * 16 + (lane & 15);
            int k = ks * 32 + (lane >> 4) * 8 + j;
            float v;
            if (n < 128)      v = Wq[k * 128 + n] * QSCALE;
            else if (n < 256) v = Wk[k * 128 + (n - 128)];
            else if (n < 384) v = Wv[k * 128 + (n - 256)];
            else              v = Wg[k * 128 + (n - 384)];
            Wfrag[idx] = f2bf(v);
        } else {
            int idx2 = idx - 65536;
            int j = idx2 & 7, lane = (idx2 >> 3) & 63, ks = (idx2 >> 9) & 3, ct = idx2 >> 11;
            int n = ct * 16 + (lane & 15);
            int k = ks * 32 + (lane >> 4) * 8 + j;
            WoFrag[idx2] = f2bf(Wo[k * 128 + n]);
        }
        return;
    }

    const int t = threadIdx.x;
    if (t < 128)      { *(f32x4*)&WbS[t * 4] = *(const f32x4*)(Wb + t * 4); }
    else if (t < 160) { int c = (t - 128) * 4; *(f32x4*)&gS[c] = *(const f32x4*)(gamma + c); }
    else if (t < 192) { int c = (t - 160) * 4; *(f32x4*)&bS[c] = *(const f32x4*)(beta + c); }
    __syncthreads();

    const int wave = t >> 6, lane = t & 63, m = lane & 15, quad = lane >> 4;
    const int p = (blockIdx.x - 320) * 64 + wave * 16 + m;

    const float* rp0 = x + (size_t)p * 128;
    f32x4 xa[4][2];
    float sum = 0.f, ssq = 0.f;
#pragma unroll
    for (int ks = 0; ks < 4; ++ks) {
        xa[ks][0] = *(const f32x4*)(rp0 + ks * 32 + quad * 8);
        xa[ks][1] = *(const f32x4*)(rp0 + ks * 32 + quad * 8 + 4);
#pragma unroll
        for (int q4 = 0; q4 < 2; ++q4) {
            f32x4 v = xa[ks][q4];
            sum += v[0] + v[1] + v[2] + v[3];
            ssq += v[0]*v[0] + v[1]*v[1] + v[2]*v[2] + v[3]*v[3];
        }
    }
    sum += __shfl_xor(sum, 16); ssq += __shfl_xor(ssq, 16);
    sum += __shfl_xor(sum, 32); ssq += __shfl_xor(ssq, 32);
    const float mu   = sum * (1.f / 128.f);
    const float rstd = rsqrtf(ssq * (1.f / 128.f) - mu * mu + 1e-5f);

    float b0 = 0.f, b1 = 0.f, b2 = 0.f, b3 = 0.f;
#pragma unroll
    for (int ks = 0; ks < 4; ++ks) {
        uint4 pkd;
        uint pw[4];
#pragma unroll
        for (int q4 = 0; q4 < 2; ++q4) {
            const int c = ks * 32 + quad * 8 + q4 * 4;
            f32x4 v = xa[ks][q4];
            float n0 = (v[0] - mu) * rstd * gS[c + 0] + bS[c + 0];
            float n1 = (v[1] - mu) * rstd * gS[c + 1] + bS[c + 1];
            float n2 = (v[2] - mu) * rstd * gS[c + 2] + bS[c + 2];
            float n3 = (v[3] - mu) * rstd * gS[c + 3] + bS[c + 3];
            pw[q4 * 2]     = pk2(n0, n1);
            pw[q4 * 2 + 1] = pk2(n2, n3);
            f32x4 w0 = *(const f32x4*)&WbS[(c + 0) * 4];
            f32x4 w1 = *(const f32x4*)&WbS[(c + 1) * 4];
            f32x4 w2 = *(const f32x4*)&WbS[(c + 2) * 4];
            f32x4 w3 = *(const f32x4*)&WbS[(c + 3) * 4];
            b0 += n0*w0[0] + n1*w1[0] + n2*w2[0] + n3*w3[0];
            b1 += n0*w0[1] + n1*w1[1] + n2*w2[1] + n3*w3[1];
            b2 += n0*w0[2] + n1*w1[2] + n2*w2[2] + n3*w3[2];
            b3 += n0*w0[3] + n1*w1[3] + n2*w2[3] + n3*w3[3];
        }
        pkd.x = pw[0]; pkd.y = pw[1]; pkd.z = pw[2]; pkd.w = pw[3];
        *(uint4*)(xn + (size_t)p * 128 + ks * 32 + quad * 8) = pkd;
    }
    b0 += __shfl_xor(b0, 16); b1 += __shfl_xor(b1, 16); b2 += __shfl_xor(b2, 16); b3 += __shfl_xor(b3, 16);
    b0 += __shfl_xor(b0, 32); b1 += __shfl_xor(b1, 32); b2 += __shfl_xor(b2, 32); b3 += __shfl_xor(b3, 32);

    if (quad == 0) {
        const int row = p >> 8, col = p & 255;
        float bb[4] = {b0, b1, b2, b3};
#pragma unroll
        for (int r = 0; r < 4; ++r) {
            int addr = (((r * 16 + (row >> 4)) * 16 + (col >> 4)) * 64 +
                        ((col & 15) >> 2) * 16 + (row & 15)) * 4 + (col & 3);
            BbF[addr] = bb[r];
        }
    }
}

// ---------------------------------------------------------------------------
// fused: grid 1024, 512 thr = 8 waves, 37376 B LDS.
// launch_bounds(512,4): 128-VGPR cap (NO spills; round-11's (512,8) forced
// a 32-VGPR allocation and 1 GB of scratch traffic).
// XCD co-location: i = ((bid>>5)<<3)|(bid&7), h = (bid>>3)&3.
// Wave w owns 32 j-rows [w*32, w*32+32) for proj AND attention.
// LDS: QK region [256][40] ushort (Qtmp, then K [k][d], pad-40);
//      VT region [32][264] ushort (V^T [d][k], pad-264).
// Phases: Qproj -> qf (same-wave rows, no barrier) -> Kproj -> Vproj ->
//         barrier -> attention (P in-register, BbF prefetched 1 kh ahead) ->
//         Gproj+gate+store (fused; G acc layout == O acc layout).
// ---------------------------------------------------------------------------
__global__ __launch_bounds__(512, 4) void fused_kernel(
    const ushort* __restrict__ xn, const ushort* __restrict__ Wfrag,
    const float* __restrict__ bg, const float* __restrict__ BbF,
    ushort* __restrict__ gvals)
{
    __shared__ __align__(16) ushort SM[18688];
    ushort* QK = SM;            // [256][40]: Qtmp, then K [k][d]
    ushort* VT = SM + 10240;    // [32][264]: V^T [d][k]

    const int t = threadIdx.x;
    const int w = t >> 6, lane = t & 63, m = lane & 15, quad = lane >> 4;
    const int b = blockIdx.x;
    const int i = ((b >> 5) << 3) | (b & 7);   // same-i blocks: same XCD (mod 8)
    const int h = (b >> 3) & 3;                //   and same 32-block window
    const ushort* xb = xn + ((size_t)i << 15);   // i*256*128

    // ---- Q proj -> Qtmp [j][40] (wave's 32 rows) ----
    {
        const ushort* Wm = Wfrag + (0 + h * 2) * 2048;
        bf16x8 wfr[2][4];
#pragma unroll
        for (int ctl = 0; ctl < 2; ++ctl)
#pragma unroll
            for (int ks = 0; ks < 4; ++ks)
                wfr[ctl][ks] = *(const bf16x8*)(Wm + ctl * 2048 + ks * 512 + lane * 8);
#pragma unroll
        for (int grp = 0; grp < 2; ++grp) {
            const int j = w * 32 + grp * 16 + m;
            bf16x8 xg[4];
            const ushort* xp = xb + (size_t)j * 128 + quad * 8;
#pragma unroll
            for (int ks = 0; ks < 4; ++ks) xg[ks] = *(const bf16x8*)(xp + ks * 32);
#pragma unroll
            for (int ctl = 0; ctl < 2; ++ctl) {
                f32x4 acc = (f32x4){0.f, 0.f, 0.f, 0.f};
#pragma unroll
                for (int ks = 0; ks < 4; ++ks) acc = MFMA32(wfr[ctl][ks], xg[ks], acc);
                uint2 u; u.x = pk2(acc[0], acc[1]); u.y = pk2(acc[2], acc[3]);
                *(uint2*)(QK + j * 40 + ctl * 16 + quad * 4) = u;
            }
        }
    }
    // qf: same-wave rows -> no barrier needed (lgkmcnt ordering suffices)
    bf16x8 qf[2];                           // B-frags: lane = j, elems = d
#pragma unroll
    for (int jt = 0; jt < 2; ++jt)
        qf[jt] = *(const bf16x8*)(QK + (w * 32 + jt * 16 + m) * 40 + quad * 8);
    asm volatile("" ::: "memory");          // block load-CSE across phases

    // ---- K proj -> QK region as K [k][40] (same-wave rows overwrite) ----
    {
        const ushort* Wm = Wfrag + (8 + h * 2) * 2048;
        bf16x8 wfr[2][4];
#pragma unroll
        for (int ctl = 0; ctl < 2; ++ctl)
#pragma unroll
            for (int ks = 0; ks < 4; ++ks)
                wfr[ctl][ks] = *(const bf16x8*)(Wm + ctl * 2048 + ks * 512 + lane * 8);
#pragma unroll
        for (int grp = 0; grp < 2; ++grp) {
            const int k = w * 32 + grp * 16 + m;
            bf16x8 xg[4];
            const ushort* xp = xb + (size_t)k * 128 + quad * 8;
#pragma unroll
            for (int ks = 0; ks < 4; ++ks) xg[ks] = *(const bf16x8*)(xp + ks * 32);
#pragma unroll
            for (int ctl = 0; ctl < 2; ++ctl) {
                f32x4 acc = (f32x4){0.f, 0.f, 0.f, 0.f};
#pragma unroll
                for (int ks = 0; ks < 4; ++ks) acc = MFMA32(wfr[ctl][ks], xg[ks], acc);
                uint2 u; u.x = pk2(acc[0], acc[1]); u.y = pk2(acc[2], acc[3]);
                *(uint2*)(QK + k * 40 + ctl * 16 + quad * 4) = u;
            }
        }
    }
    asm volatile("" ::: "memory");

    // ---- V proj -> VT [d][264] (transposed) ----
    {
        const ushort* Wm = Wfrag + (16 + h * 2) * 2048;
        bf16x8 wfr[2][4];
#pragma unroll
        for (int ctl = 0; ctl < 2; ++ctl)
#pragma unroll
            for (int ks = 0; ks < 4; ++ks)
                wfr[ctl][ks] = *(const bf16x8*)(Wm + ctl * 2048 + ks * 512 + lane * 8);
#pragma unroll
        for (int grp = 0; grp < 2; ++grp) {
            const int k = w * 32 + grp * 16 + m;
            bf16x8 xg[4];
            const ushort* xp = xb + (size_t)k * 128 + quad * 8;
#pragma unroll
            for (int ks = 0; ks < 4; ++ks) xg[ks] = *(const bf16x8*)(xp + ks * 32);
#pragma unroll
            for (int ctl = 0; ctl < 2; ++ctl) {
                f32x4 acc = (f32x4){0.f, 0.f, 0.f, 0.f};
#pragma unroll
                for (int ks = 0; ks < 4; ++ks) acc = MFMA32(wfr[ctl][ks], xg[ks], acc);
#pragma unroll
                for (int r = 0; r < 4; ++r)
                    VT[(ctl * 16 + quad * 4 + r) * 264 + k] = f2bf(acc[r]);
            }
        }
    }
    __syncthreads();    // K, VT visible to all waves

    // ---- attention: 16-wide k-tiles; P in registers; BbF prefetch 1 ahead --
    f32x4 O[2][2];
    float lsum[2];
#pragma unroll
    for (int jt = 0; jt < 2; ++jt) {
        O[jt][0] = (f32x4){0.f, 0.f, 0.f, 0.f};
        O[jt][1] = (f32x4){0.f, 0.f, 0.f, 0.f};
        lsum[jt] = 0.f;
    }
    const float* bb = BbF + ((size_t)(h * 16 + w * 2) << 12) + (lane << 2);

    f32x4 Scur[2], Snxt[2];
    Scur[0] = *(const f32x4*)(bb);
    Scur[1] = *(const f32x4*)(bb + 4096);

    for (int kh = 0; kh < 16; ++kh) {
        if (kh < 15) {
            Snxt[0] = *(const f32x4*)(bb + ((kh + 1) << 8));
            Snxt[1] = *(const f32x4*)(bb + 4096 + ((kh + 1) << 8));
        }
        bf16x8 kf = *(const bf16x8*)(QK + (kh * 16 + m) * 40 + quad * 8);  // A: lane=k, elems=d
        bf16x4 vf[2];                                                       // A: lane=d, elems=k
#pragma unroll
        for (int dt = 0; dt < 2; ++dt) {
            uint2 vv = *(const uint2*)(VT + (dt * 16 + m) * 264 + kh * 16 + quad * 4);
            vf[dt] = __builtin_bit_cast(bf16x4, vv);
        }
#pragma unroll
        for (int jt = 0; jt < 2; ++jt) {
            f32x4 S = MFMA32(kf, qf[jt], Scur[jt]);
            float p0 = __expf(S[0]), p1 = __expf(S[1]);
            float p2 = __expf(S[2]), p3 = __expf(S[3]);
            lsum[jt] += p0 + p1 + p2 + p3;
            uint2 pu; pu.x = pk2(p0, p1); pu.y = pk2(p2, p3);
            bf16x4 pf = __builtin_bit_cast(bf16x4, pu);   // B: lane=j, k=quad*4+e
#pragma unroll
            for (int dt = 0; dt < 2; ++dt)
                O[jt][dt] = MFMA16(vf[dt], pf, O[jt][dt]);
        }
        Scur[0] = Snxt[0];
        Scur[1] = Snxt[1];
    }

    // row sums across quads
#pragma unroll
    for (int jt = 0; jt < 2; ++jt) {
        float s = lsum[jt];
        s += __shfl_xor(s, 16);
        s += __shfl_xor(s, 32);
        lsum[jt] = 1.f / s;
    }

    // ---- G proj fused with gating + store (G acc layout == O acc layout) ----
    {
        const ushort* Wm = Wfrag + (24 + h * 2) * 2048;
        bf16x8 wfr[2][4];
        f32x4 bg4[2];
#pragma unroll
        for (int ctl = 0; ctl < 2; ++ctl) {
#pragma unroll
            for (int ks = 0; ks < 4; ++ks)
                wfr[ctl][ks] = *(const bf16x8*)(Wm + ctl * 2048 + ks * 512 + lane * 8);
            bg4[ctl] = *(const f32x4*)(bg + h * 32 + ctl * 16 + quad * 4);
        }
#pragma unroll
        for (int grp = 0; grp < 2; ++grp) {
            const int j = w * 32 + grp * 16 + m;
            const float rl = lsum[grp];
            bf16x8 xg[4];
            const ushort* xp = xb + (size_t)j * 128 + quad * 8;
#pragma unroll
            for (int ks = 0; ks < 4; ++ks) xg[ks] = *(const bf16x8*)(xp + ks * 32);
#pragma unroll
            for (int ctl = 0; ctl < 2; ++ctl) {
                f32x4 acc = (f32x4){0.f, 0.f, 0.f, 0.f};
#pragma unroll
                for (int ks = 0; ks < 4; ++ks) acc = MFMA32(wfr[ctl][ks], xg[ks], acc);
                float g0 = 1.f / (1.f + __expf(-(acc[0] + bg4[ctl][0])));
                float g1 = 1.f / (1.f + __expf(-(acc[1] + bg4[ctl][1])));
                float g2 = 1.f / (1.f + __expf(-(acc[2] + bg4[ctl][2])));
                float g3 = 1.f / (1.f + __expf(-(acc[3] + bg4[ctl][3])));
                float v0 = O[grp][ctl][0] * rl * g0;
                float v1 = O[grp][ctl][1] * rl * g1;
                float v2 = O[grp][ctl][2] * rl * g2;
                float v3 = O[grp][ctl][3] * rl * g3;
                uint2 u; u.x = pk2(v0, v1); u.y = pk2(v2, v3);
                *(uint2*)(gvals + (size_t)(i * 256 + j) * 128 + h * 32 + ctl * 16 + quad * 4) = u;
            }
        }
    }
}

// ---------------------------------------------------------------------------
// oproj: A = WoFrag, B = gvals rows -> D[ncol][p]; float4 stores + bo.
// ---------------------------------------------------------------------------
__global__ __launch_bounds__(256) void oproj_kernel(
    const ushort* __restrict__ gvals, const ushort* __restrict__ WoFrag,
    const float* __restrict__ bo, float* __restrict__ out)
{
    __shared__ ushort Bs[8 * 2048];
    const int t = threadIdx.x;
    const int wave = t >> 6, lane = t & 63, m = lane & 15, quad = lane >> 4;
    const int p0 = blockIdx.x * 64;
    {
        const uint4* src = (const uint4*)WoFrag;
        uint4* dst = (uint4*)Bs;
#pragma unroll
        for (int r = 0; r < 8; ++r) dst[r * 256 + t] = src[r * 256 + t];
    }
    bf16x8 gf[4];
    const int p = p0 + wave * 16 + m;
#pragma unroll
    for (int ks = 0; ks < 4; ++ks)
        gf[ks] = *(const bf16x8*)(gvals + (size_t)p * 128 + ks * 32 + quad * 8);
    __syncthreads();

#pragma unroll
    for (int ct = 0; ct < 8; ++ct) {
        f32x4 acc = (f32x4){0.f, 0.f, 0.f, 0.f};
#pragma unroll
        for (int ks = 0; ks < 4; ++ks) {
            bf16x8 wfr = ((const bf16x8*)Bs)[(ct * 4 + ks) * 64 + lane];
            acc = MFMA32(wfr, gf[ks], acc);
        }
        const int c0 = ct * 16 + quad * 4;
        f32x4 bov = *(const f32x4*)(bo + c0);
        float4 v = make_float4(acc[0] + bov[0], acc[1] + bov[1],
                               acc[2] + bov[2], acc[3] + bov[3]);
        *(float4*)(&out[(size_t)p * 128 + c0]) = v;
    }
}

// ---------------------------------------------------------------------------
extern "C" void kernel_launch(void* const* d_in, const int* in_sizes, int n_in,
                              void* d_out, int out_size, void* d_ws, size_t ws_size,
                              hipStream_t stream) {
    const float* x     = (const float*)d_in[0];
    const float* gamma = (const float*)d_in[1];
    const float* beta  = (const float*)d_in[2];
    const float* Wq    = (const float*)d_in[3];
    const float* Wk    = (const float*)d_in[4];
    const float* Wv    = (const float*)d_in[5];
    const float* Wb    = (const float*)d_in[6];
    const float* Wg    = (const float*)d_in[7];
    const float* bg    = (const float*)d_in[8];
    const float* Wo    = (const float*)d_in[9];
    const float* bo    = (const float*)d_in[10];

    ushort* ws      = (ushort*)d_ws;
    ushort* Wfrag   = ws;                                // 65536 ushorts
    ushort* WoFragp = ws + 65536;                        // 16384 ushorts
    ushort* xn      = ws + 81920;                        // 8388608 ushorts (16 MB)
    ushort* gvals   = ws + 81920 + 8388608;              // 8388608 ushorts (16 MB)
    float*  BbF     = (float*)(ws + 81920 + 2 * 8388608);  // 262144 fp32 (1 MB)

    prep_bias_kernel<<<1344, 256, 0, stream>>>(Wq, Wk, Wv, Wg, Wo, Wb,
                                               x, gamma, beta,
                                               Wfrag, WoFragp, xn, BbF);
    fused_kernel<<<1024, 512, 0, stream>>>(xn, Wfrag, bg, BbF, gvals);
    oproj_kernel<<<1024, 256, 0, stream>>>(gvals, WoFragp, bo, (float*)d_out);
}

// Round 9
// 162.458 us; speedup vs baseline: 2.6885x; 1.1862x over previous
//
#include <hip/hip_runtime.h>
#include <hip/hip_bf16.h>

// TriangleAttentionStartingNode  B=1, N=256, C_Z=128, H=4, D=32, TOTAL=128
// Round 14: round 13 + compile fix (braced init list can't be a macro arg;
// use named ZERO4). Design unchanged:
//   monolithic per-i fused kernel (r7 winner) with all proven improvements:
//   - P in registers via 16-wide k-tiles + MFMA16 (r10/r12-proven layouts)
//   - G-proj after attention, gate in regs (r9/r12-proven; no global bounce)
//   - xn precomputed bf16 (prep_bias), no in-kernel LN
//   - EbF = exp(bias): QK MFMAs start from zero acc (no global load on the
//     MFMA critical path); eb loads independent, batched 8-per-kh
//   - weights direct from global (r10-proven), 3 barriers total
//   - LDS 128 KB: K [4][128][64]swz + VT [4][32][256]swz; per-wave Qtmp
//     overlays the wave's OWN future K sub-region; gvals bounce overlays K
//   - launch_bounds(512,1): no allocator spill trap (r11/r12 lessons)

#define QSCALE 0.17677669529663687f  // 1/sqrt(32)

typedef __attribute__((ext_vector_type(8))) short bf16x8;
typedef __attribute__((ext_vector_type(4))) short bf16x4;
typedef __attribute__((ext_vector_type(4))) float f32x4;

#define MFMA32(a, b, c) __builtin_amdgcn_mfma_f32_16x16x32_bf16((a), (b), (c), 0, 0, 0)

__device__ __forceinline__ f32x4 mfma16_asm(bf16x4 a, bf16x4 b, f32x4 c) {
    f32x4 d;
    asm volatile("v_mfma_f32_16x16x16_bf16 %0, %1, %2, %3"
                 : "=v"(d) : "v"(a), "v"(b), "v"(c));
    return d;
}

#if !defined(__HIP_DEVICE_COMPILE__)
#define MFMA16(a, b, c) (c)   /* host pass: parsed only, never executed */
#elif __has_builtin(__builtin_amdgcn_mfma_f32_16x16x16bf16_1k)
#define MFMA16(a, b, c) __builtin_amdgcn_mfma_f32_16x16x16bf16_1k((a), (b), (c), 0, 0, 0)
#else
#define MFMA16(a, b, c) mfma16_asm((a), (b), (c))
#endif

__device__ __forceinline__ ushort f2bf(float f) {
    uint32_t u = __builtin_bit_cast(uint32_t, f);
    uint32_t r = (u + 0x7FFFu + ((u >> 16) & 1u)) >> 16;  // RNE
    return (ushort)r;
}
__device__ __forceinline__ uint pk2(float a, float b) {   // v_cvt_pk_bf16_f32
    union { __hip_bfloat162 h; uint u; } cv;
    cv.h = __float22bfloat162_rn(make_float2(a, b));
    return cv.u;
}

// ---------------------------------------------------------------------------
// prep_bias: bid<320 -> prep: Wfrag[ct][ks][lane][j] bf16 with
//   n = ct*16+(lane&15), k = ks*32+(lane>>4)*8+j, value W^T[n][k]
//   (n: 0..127 Wq*QSCALE, 128..255 Wk, 256..383 Wv, 384..511 Wg); WoFrag same.
// bid>=320 -> bias: LN in-register; write xn bf16 [p][128]; dot with Wb ->
//   EbF = exp(bias) fp32 scattered in attn-frag order (row=j, col=k):
//   addr = (((h*16+j/16)*16+k/16)*64 + ((k&15)>>2)*16 + (j&15))*4 + (k&3)
// ---------------------------------------------------------------------------
__global__ __launch_bounds__(256) void prep_bias_kernel(
    const float* __restrict__ Wq, const float* __restrict__ Wk, const float* __restrict__ Wv,
    const float* __restrict__ Wg, const float* __restrict__ Wo, const float* __restrict__ Wb,
    const float* __restrict__ x, const float* __restrict__ gamma, const float* __restrict__ beta,
    ushort* __restrict__ Wfrag, ushort* __restrict__ WoFrag,
    ushort* __restrict__ xn, float* __restrict__ EbF)
{
    __shared__ float WbS[512];
    __shared__ float gS[128];
    __shared__ float bS[128];

    if (blockIdx.x < 320) {
        int idx = blockIdx.x * 256 + threadIdx.x;
        if (idx < 65536) {
            int j = idx & 7, lane = (idx >> 3) & 63, ks = (idx >> 9) & 3, ct = idx >> 11;
            int n = ct * 16 + (lane & 15);
            int k = ks * 32 + (lane >> 4) * 8 + j;
            float v;
            if (n < 128)      v = Wq[k * 128 + n] * QSCALE;
            else if (n < 256) v = Wk[k * 128 + (n - 128)];
            else if (n < 384) v = Wv[k * 128 + (n - 256)];
            else              v = Wg[k * 128 + (n - 384)];
            Wfrag[idx] = f2bf(v);
        } else {
            int idx2 = idx - 65536;
            int j = idx2 & 7, lane = (idx2 >> 3) & 63, ks = (idx2 >> 9) & 3, ct = idx2 >> 11;
            int n = ct * 16 + (lane & 15);
            int k = ks * 32 + (lane >> 4) * 8 + j;
            WoFrag[idx2] = f2bf(Wo[k * 128 + n]);
        }
        return;
    }

    const int t = threadIdx.x;
    if (t < 128)      { *(f32x4*)&WbS[t * 4] = *(const f32x4*)(Wb + t * 4); }
    else if (t < 160) { int c = (t - 128) * 4; *(f32x4*)&gS[c] = *(const f32x4*)(gamma + c); }
    else if (t < 192) { int c = (t - 160) * 4; *(f32x4*)&bS[c] = *(const f32x4*)(beta + c); }
    __syncthreads();

    const int wave = t >> 6, lane = t & 63, m = lane & 15, quad = lane >> 4;
    const int p = (blockIdx.x - 320) * 64 + wave * 16 + m;

    const float* rp0 = x + (size_t)p * 128;
    f32x4 xa[4][2];
    float sum = 0.f, ssq = 0.f;
#pragma unroll
    for (int ks = 0; ks < 4; ++ks) {
        xa[ks][0] = *(const f32x4*)(rp0 + ks * 32 + quad * 8);
        xa[ks][1] = *(const f32x4*)(rp0 + ks * 32 + quad * 8 + 4);
#pragma unroll
        for (int q4 = 0; q4 < 2; ++q4) {
            f32x4 v = xa[ks][q4];
            sum += v[0] + v[1] + v[2] + v[3];
            ssq += v[0]*v[0] + v[1]*v[1] + v[2]*v[2] + v[3]*v[3];
        }
    }
    sum += __shfl_xor(sum, 16); ssq += __shfl_xor(ssq, 16);
    sum += __shfl_xor(sum, 32); ssq += __shfl_xor(ssq, 32);
    const float mu   = sum * (1.f / 128.f);
    const float rstd = rsqrtf(ssq * (1.f / 128.f) - mu * mu + 1e-5f);

    float b0 = 0.f, b1 = 0.f, b2 = 0.f, b3 = 0.f;
#pragma unroll
    for (int ks = 0; ks < 4; ++ks) {
        uint4 pkd;
        uint pw[4];
#pragma unroll
        for (int q4 = 0; q4 < 2; ++q4) {
            const int c = ks * 32 + quad * 8 + q4 * 4;
            f32x4 v = xa[ks][q4];
            float n0 = (v[0] - mu) * rstd * gS[c + 0] + bS[c + 0];
            float n1 = (v[1] - mu) * rstd * gS[c + 1] + bS[c + 1];
            float n2 = (v[2] - mu) * rstd * gS[c + 2] + bS[c + 2];
            float n3 = (v[3] - mu) * rstd * gS[c + 3] + bS[c + 3];
            pw[q4 * 2]     = pk2(n0, n1);
            pw[q4 * 2 + 1] = pk2(n2, n3);
            f32x4 w0 = *(const f32x4*)&WbS[(c + 0) * 4];
            f32x4 w1 = *(const f32x4*)&WbS[(c + 1) * 4];
            f32x4 w2 = *(const f32x4*)&WbS[(c + 2) * 4];
            f32x4 w3 = *(const f32x4*)&WbS[(c + 3) * 4];
            b0 += n0*w0[0] + n1*w1[0] + n2*w2[0] + n3*w3[0];
            b1 += n0*w0[1] + n1*w1[1] + n2*w2[1] + n3*w3[1];
            b2 += n0*w0[2] + n1*w1[2] + n2*w2[2] + n3*w3[2];
            b3 += n0*w0[3] + n1*w1[3] + n2*w2[3] + n3*w3[3];
        }
        pkd.x = pw[0]; pkd.y = pw[1]; pkd.z = pw[2]; pkd.w = pw[3];
        *(uint4*)(xn + (size_t)p * 128 + ks * 32 + quad * 8) = pkd;
    }
    b0 += __shfl_xor(b0, 16); b1 += __shfl_xor(b1, 16); b2 += __shfl_xor(b2, 16); b3 += __shfl_xor(b3, 16);
    b0 += __shfl_xor(b0, 32); b1 += __shfl_xor(b1, 32); b2 += __shfl_xor(b2, 32); b3 += __shfl_xor(b3, 32);

    if (quad == 0) {
        const int row = p >> 8, col = p & 255;
        float bb[4] = {b0, b1, b2, b3};
#pragma unroll
        for (int r = 0; r < 4; ++r) {
            int addr = (((r * 16 + (row >> 4)) * 16 + (col >> 4)) * 64 +
                        ((col & 15) >> 2) * 16 + (row & 15)) * 4 + (col & 3);
            EbF[addr] = __expf(bb[r]);
        }
    }
}

// ---------------------------------------------------------------------------
// fused: grid 256 (block = pair-row i), 512 thr = 8 waves (h = w>>1,
// half = w&1; wave owns j-rows [half*128, half*128+128) of head h).
// LDS 131072 B (1 blk/CU): KL 64 KB (per-wave Qtmp [128][32] overlay at
// w*4096 == the wave's own K[h] half -> no hazard; K [4][128][64] swz;
// gvals [256][128] swz for the fused oproj), VT 64 KB ([4][32][256] swz).
// Phases: Qproj -> qf -> Kproj -> Vproj -> BARRIER -> attention (P in-reg,
// EbF multiply, zero-acc MFMA) -> Gproj+gate (regs) -> BARRIER -> gvals->LDS
// -> BARRIER -> oproj (Wo direct from global) -> float4 out + bo.
// ---------------------------------------------------------------------------
__global__ __launch_bounds__(512, 1) void fused_kernel(
    const ushort* __restrict__ xn, const ushort* __restrict__ Wfrag,
    const float* __restrict__ bg, const float* __restrict__ EbF,
    const ushort* __restrict__ WoFrag, const float* __restrict__ bo,
    float* __restrict__ out)
{
    extern __shared__ __align__(16) ushort SM[];
    ushort* KL = SM;            // 32768 ushorts
    ushort* VT = SM + 32768;    // 32768 ushorts

    const f32x4 ZERO4 = {0.f, 0.f, 0.f, 0.f};

    const int t = threadIdx.x;
    const int w = t >> 6, lane = t & 63, m = lane & 15, quad = lane >> 4;
    const int i = blockIdx.x;
    const int h = w >> 1, half = w & 1;
    const int jbase = half * 128;
    const ushort* xb = xn + ((size_t)i << 15);   // i*256*128

    // ---- Q proj -> per-wave Qtmp [128][32] at KL + w*4096 ----
    {
        const ushort* Wm = Wfrag + (h * 2) * 2048;
        bf16x8 wfr[2][4];
#pragma unroll
        for (int ctl = 0; ctl < 2; ++ctl)
#pragma unroll
            for (int ks = 0; ks < 4; ++ks)
                wfr[ctl][ks] = *(const bf16x8*)(Wm + ctl * 2048 + ks * 512 + lane * 8);
#pragma unroll
        for (int grp = 0; grp < 8; ++grp) {
            const int jloc = grp * 16 + m;
            bf16x8 xg[4];
            const ushort* xp = xb + (size_t)(jbase + jloc) * 128 + quad * 8;
#pragma unroll
            for (int ks = 0; ks < 4; ++ks) xg[ks] = *(const bf16x8*)(xp + ks * 32);
#pragma unroll
            for (int ctl = 0; ctl < 2; ++ctl) {
                f32x4 acc = ZERO4;
#pragma unroll
                for (int ks = 0; ks < 4; ++ks) acc = MFMA32(wfr[ctl][ks], xg[ks], acc);
                const int c = ctl * 16 + quad * 4;
                const int idx = (w * 4096 + jloc * 32 + c) ^ ((jloc & 3) << 3);
                uint2 u; u.x = pk2(acc[0], acc[1]); u.y = pk2(acc[2], acc[3]);
                *(uint2*)(KL + idx) = u;
            }
        }
    }
    // qf: own region, program order (ds ordering within wave)
    bf16x8 qf[8];
#pragma unroll
    for (int jt = 0; jt < 8; ++jt) {
        const int jloc = jt * 16 + m;
        const int idx = (w * 4096 + jloc * 32 + quad * 8) ^ ((jloc & 3) << 3);
        qf[jt] = *(const bf16x8*)(KL + idx);
    }
    asm volatile("" ::: "memory");

    // ---- K proj -> K [h][k/2][64] swz; wave's k rows == its own Qtmp region
    {
        const ushort* Wm = Wfrag + (8 + h * 2) * 2048;
        bf16x8 wfr[2][4];
#pragma unroll
        for (int ctl = 0; ctl < 2; ++ctl)
#pragma unroll
            for (int ks = 0; ks < 4; ++ks)
                wfr[ctl][ks] = *(const bf16x8*)(Wm + ctl * 2048 + ks * 512 + lane * 8);
#pragma unroll
        for (int grp = 0; grp < 8; ++grp) {
            const int k = jbase + grp * 16 + m;
            bf16x8 xg[4];
            const ushort* xp = xb + (size_t)k * 128 + quad * 8;
#pragma unroll
            for (int ks = 0; ks < 4; ++ks) xg[ks] = *(const bf16x8*)(xp + ks * 32);
#pragma unroll
            for (int ctl = 0; ctl < 2; ++ctl) {
                f32x4 acc = ZERO4;
#pragma unroll
                for (int ks = 0; ks < 4; ++ks) acc = MFMA32(wfr[ctl][ks], xg[ks], acc);
                const int d0 = ctl * 16 + quad * 4;
                const int idx = (h * 8192 + (k >> 1) * 64 + (k & 1) * 32 + d0) ^ (((k >> 1) & 7) << 3);
                uint2 u; u.x = pk2(acc[0], acc[1]); u.y = pk2(acc[2], acc[3]);
                *(uint2*)(KL + idx) = u;
            }
        }
    }

    // ---- V proj -> VT [h][d][k] swz (transposed scalar stores) ----
    {
        const ushort* Wm = Wfrag + (16 + h * 2) * 2048;
        bf16x8 wfr[2][4];
#pragma unroll
        for (int ctl = 0; ctl < 2; ++ctl)
#pragma unroll
            for (int ks = 0; ks < 4; ++ks)
                wfr[ctl][ks] = *(const bf16x8*)(Wm + ctl * 2048 + ks * 512 + lane * 8);
#pragma unroll
        for (int grp = 0; grp < 8; ++grp) {
            const int k = jbase + grp * 16 + m;
            bf16x8 xg[4];
            const ushort* xp = xb + (size_t)k * 128 + quad * 8;
#pragma unroll
            for (int ks = 0; ks < 4; ++ks) xg[ks] = *(const bf16x8*)(xp + ks * 32);
#pragma unroll
            for (int ctl = 0; ctl < 2; ++ctl) {
                f32x4 acc = ZERO4;
#pragma unroll
                for (int ks = 0; ks < 4; ++ks) acc = MFMA32(wfr[ctl][ks], xg[ks], acc);
#pragma unroll
                for (int r = 0; r < 4; ++r) {
                    const int d = ctl * 16 + quad * 4 + r;
                    const int idx = ((h * 32 + d) * 256 + k) ^ ((d & 7) << 3);
                    VT[idx] = f2bf(acc[r]);
                }
            }
        }
    }
    __syncthreads();    // K, VT visible to all waves

    // ---- attention: 16-wide k-tiles; P in registers; eb batched per kh ----
    f32x4 O[8][2];
    float lsum[8];
#pragma unroll
    for (int jt = 0; jt < 8; ++jt) {
        O[jt][0] = ZERO4;
        O[jt][1] = ZERO4;
        lsum[jt] = 0.f;
    }
    const float* ebB = EbF + ((size_t)(h * 16 + half * 8) << 12) + (lane << 2);

    for (int kh = 0; kh < 16; ++kh) {
        f32x4 eb[8];
#pragma unroll
        for (int jt = 0; jt < 8; ++jt)
            eb[jt] = *(const f32x4*)(ebB + (jt << 12) + (kh << 8));
        const int k = kh * 16 + m;
        const int kidx = (h * 8192 + (k >> 1) * 64 + (k & 1) * 32 + quad * 8) ^ (((k >> 1) & 7) << 3);
        bf16x8 kf = *(const bf16x8*)(KL + kidx);            // A: lane=k, elems=d
        bf16x4 vf[2];                                       // A: lane=d, elems=k
#pragma unroll
        for (int dt = 0; dt < 2; ++dt) {
            const int d = dt * 16 + m;
            const int vidx = ((h * 32 + d) * 256 + kh * 16 + quad * 4) ^ ((d & 7) << 3);
            uint2 vv = *(const uint2*)(VT + vidx);
            vf[dt] = __builtin_bit_cast(bf16x4, vv);
        }
#pragma unroll
        for (int jt = 0; jt < 8; ++jt) {
            f32x4 S = MFMA32(kf, qf[jt], ZERO4);
            float p0 = __expf(S[0]) * eb[jt][0];
            float p1 = __expf(S[1]) * eb[jt][1];
            float p2 = __expf(S[2]) * eb[jt][2];
            float p3 = __expf(S[3]) * eb[jt][3];
            lsum[jt] += p0 + p1 + p2 + p3;
            uint2 pu; pu.x = pk2(p0, p1); pu.y = pk2(p2, p3);
            bf16x4 pf = __builtin_bit_cast(bf16x4, pu);     // B: lane=j, k=quad*4+e
#pragma unroll
            for (int dt = 0; dt < 2; ++dt)
                O[jt][dt] = MFMA16(vf[dt], pf, O[jt][dt]);
        }
    }

    // row sums across quads
#pragma unroll
    for (int jt = 0; jt < 8; ++jt) {
        float s = lsum[jt];
        s += __shfl_xor(s, 16);
        s += __shfl_xor(s, 32);
        lsum[jt] = 1.f / s;
    }

    // ---- G proj + gate in registers (G acc layout == O acc layout) ----
    uint2 gva[8][2];
    {
        const ushort* Wm = Wfrag + (24 + h * 2) * 2048;
        bf16x8 wfr[2][4];
        f32x4 bg4[2];
#pragma unroll
        for (int ctl = 0; ctl < 2; ++ctl) {
#pragma unroll
            for (int ks = 0; ks < 4; ++ks)
                wfr[ctl][ks] = *(const bf16x8*)(Wm + ctl * 2048 + ks * 512 + lane * 8);
            bg4[ctl] = *(const f32x4*)(bg + h * 32 + ctl * 16 + quad * 4);
        }
#pragma unroll
        for (int grp = 0; grp < 8; ++grp) {
            const float rl = lsum[grp];
            bf16x8 xg[4];
            const ushort* xp = xb + (size_t)(jbase + grp * 16 + m) * 128 + quad * 8;
#pragma unroll
            for (int ks = 0; ks < 4; ++ks) xg[ks] = *(const bf16x8*)(xp + ks * 32);
#pragma unroll
            for (int ctl = 0; ctl < 2; ++ctl) {
                f32x4 acc = ZERO4;
#pragma unroll
                for (int ks = 0; ks < 4; ++ks) acc = MFMA32(wfr[ctl][ks], xg[ks], acc);
                float g0 = 1.f / (1.f + __expf(-(acc[0] + bg4[ctl][0])));
                float g1 = 1.f / (1.f + __expf(-(acc[1] + bg4[ctl][1])));
                float g2 = 1.f / (1.f + __expf(-(acc[2] + bg4[ctl][2])));
                float g3 = 1.f / (1.f + __expf(-(acc[3] + bg4[ctl][3])));
                float v0 = O[grp][ctl][0] * rl * g0;
                float v1 = O[grp][ctl][1] * rl * g1;
                float v2 = O[grp][ctl][2] * rl * g2;
                float v3 = O[grp][ctl][3] * rl * g3;
                gva[grp][ctl].x = pk2(v0, v1);
                gva[grp][ctl].y = pk2(v2, v3);
            }
        }
    }
    __syncthreads();    // all attention K/VT reads done before KL overwrite

    // ---- gvals -> KL [256][128] swz ----
#pragma unroll
    for (int grp = 0; grp < 8; ++grp) {
        const int j = jbase + grp * 16 + m;
#pragma unroll
        for (int ctl = 0; ctl < 2; ++ctl) {
            const int c0 = h * 32 + ctl * 16 + quad * 4;
            const int idx = (j * 128 + c0) ^ ((j & 7) << 3);
            *(uint2*)(KL + idx) = gva[grp][ctl];
        }
    }
    __syncthreads();    // gvals complete

    // ---- oproj: wave w -> rows w*32..w*32+31; Wo frags direct from global --
    bf16x8 gf[2][4];
#pragma unroll
    for (int grp = 0; grp < 2; ++grp) {
        const int pl = w * 32 + grp * 16 + m;
#pragma unroll
        for (int ks = 0; ks < 4; ++ks) {
            const int idx = (pl * 128 + ks * 32 + quad * 8) ^ ((pl & 7) << 3);
            gf[grp][ks] = *(const bf16x8*)(KL + idx);
        }
    }
#pragma unroll
    for (int ct = 0; ct < 8; ++ct) {
        bf16x8 wfr[4];
#pragma unroll
        for (int ks = 0; ks < 4; ++ks)
            wfr[ks] = *(const bf16x8*)(WoFrag + (ct * 4 + ks) * 512 + lane * 8);
        const int c0 = ct * 16 + quad * 4;
        f32x4 bov = *(const f32x4*)(bo + c0);
#pragma unroll
        for (int grp = 0; grp < 2; ++grp) {
            f32x4 acc = ZERO4;
#pragma unroll
            for (int ks = 0; ks < 4; ++ks) acc = MFMA32(wfr[ks], gf[grp][ks], acc);
            const int p = i * 256 + w * 32 + grp * 16 + m;
            float4 v = make_float4(acc[0] + bov[0], acc[1] + bov[1],
                                   acc[2] + bov[2], acc[3] + bov[3]);
            *(float4*)(out + (size_t)p * 128 + c0) = v;
        }
    }
}

// ---------------------------------------------------------------------------
extern "C" void kernel_launch(void* const* d_in, const int* in_sizes, int n_in,
                              void* d_out, int out_size, void* d_ws, size_t ws_size,
                              hipStream_t stream) {
    const float* x     = (const float*)d_in[0];
    const float* gamma = (const float*)d_in[1];
    const float* beta  = (const float*)d_in[2];
    const float* Wq    = (const float*)d_in[3];
    const float* Wk    = (const float*)d_in[4];
    const float* Wv    = (const float*)d_in[5];
    const float* Wb    = (const float*)d_in[6];
    const float* Wg    = (const float*)d_in[7];
    const float* bg    = (const float*)d_in[8];
    const float* Wo    = (const float*)d_in[9];
    const float* bo    = (const float*)d_in[10];

    ushort* ws      = (ushort*)d_ws;
    ushort* Wfrag   = ws;                                // 65536 ushorts
    ushort* WoFragp = ws + 65536;                        // 16384 ushorts
    ushort* xn      = ws + 81920;                        // 8388608 ushorts (16 MB)
    float*  EbF     = (float*)(ws + 81920 + 8388608);    // 262144 fp32 (1 MB)

    static bool attr_set = false;
    if (!attr_set) {
        (void)hipFuncSetAttribute((const void*)fused_kernel,
                                  hipFuncAttributeMaxDynamicSharedMemorySize, 131072);
        attr_set = true;
    }

    prep_bias_kernel<<<1344, 256, 0, stream>>>(Wq, Wk, Wv, Wg, Wo, Wb,
                                               x, gamma, beta,
                                               Wfrag, WoFragp, xn, EbF);
    fused_kernel<<<256, 512, 131072, stream>>>(xn, Wfrag, bg, EbF,
                                               WoFragp, bo, (float*)d_out);
}